// Round 3
// baseline (709.769 us; speedup 1.0000x reference)
//
#include <hip/hip_runtime.h>
#include <math.h>

// ---------------------------------------------------------------------------
// GAT 2-layer + mean-pool + classifier, fp32 end-to-end.
//  - CSR(dst) built on-device each call
//  - softmax denominators factor out; no segment-max (logits O(1), fp32 safe)
//  - self loops analytic; dst-centric aggregation, float4 channels, no atomics
//  - aggregation: 2 edge-groups/dst + 4-edge software pipeline for MLP
// ---------------------------------------------------------------------------

// ---------------- CSR build ----------------

__global__ void k_zero(int* __restrict__ p, int n){
  int i = blockIdx.x * 256 + threadIdx.x;
  if (i < n) p[i] = 0;
}

__global__ void k_hist(const int* __restrict__ dst, int* __restrict__ counts, int e){
  int i = blockIdx.x * 256 + threadIdx.x;
  if (i < e) atomicAdd(&counts[dst[i]], 1);
}

__global__ __launch_bounds__(1024) void k_scan1(const int* __restrict__ counts,
                                                int* __restrict__ tmp,
                                                int* __restrict__ bsum, int n){
  __shared__ int sh[1024];
  int t = threadIdx.x;
  int i = blockIdx.x * 1024 + t;
  sh[t] = (i < n) ? counts[i] : 0;
  __syncthreads();
  for (int o = 1; o < 1024; o <<= 1){
    int x = (t >= o) ? sh[t - o] : 0;
    __syncthreads();
    sh[t] += x;
    __syncthreads();
  }
  if (i < n) tmp[i] = sh[t];
  if (t == 1023) bsum[blockIdx.x] = sh[t];
}

__global__ void k_scan2(const int* __restrict__ bsum, int* __restrict__ bbase, int nb){
  if (threadIdx.x == 0 && blockIdx.x == 0){
    int run = 0;
    for (int b = 0; b < nb; ++b){ bbase[b] = run; run += bsum[b]; }
  }
}

__global__ void k_scan3(const int* __restrict__ tmp, const int* __restrict__ bbase,
                        int* __restrict__ off, int* __restrict__ cur, int n){
  int i = blockIdx.x * 256 + threadIdx.x;
  if (i < n){
    int v = tmp[i] + bbase[i >> 10];
    off[i + 1] = v;
    cur[i + 1] = v;
    if (i == 0){ off[0] = 0; cur[0] = 0; }
  }
}

__global__ void k_scatter(const int* __restrict__ src, const int* __restrict__ dst,
                          int* __restrict__ cur, int* __restrict__ csr, int e){
  int i = blockIdx.x * 256 + threadIdx.x;
  if (i < e){
    int d = dst[i];
    int pos = atomicAdd(&cur[d], 1);
    csr[pos] = src[i];
  }
}

// ---------------- fused GEMM (X @ W) + attention dot epilogue ----------------

template<int OUTC, int HEADS, int CGN, int RPT>
__global__ __launch_bounds__(256) void k_gemm_att(
    const float* __restrict__ X, const float* __restrict__ W,
    const float* __restrict__ att_s, const float* __restrict__ att_d,
    float* __restrict__ H, float* __restrict__ ASRC, float* __restrict__ ADST, int n)
{
  constexpr int K = 128;
  constexpr int KC = 32;
  constexpr int ROWS = (256 / CGN) * RPT;   // 128
  constexpr int CGPH = CGN / HEADS;

  __shared__ float ws[KC][OUTC];
  __shared__ float xs[ROWS][KC + 1];
  __shared__ float pS[ROWS][CGN];
  __shared__ float pD[ROWS][CGN];

  const int tid  = threadIdx.x;
  const int cg   = tid % CGN;
  const int slot = tid / CGN;
  const int row0 = blockIdx.x * ROWS;

  float acc[RPT][16];
  #pragma unroll
  for (int r = 0; r < RPT; ++r)
    #pragma unroll
    for (int j = 0; j < 16; ++j) acc[r][j] = 0.f;

  for (int kc = 0; kc < K; kc += KC){
    {
      const float4* Wv = (const float4*)(W + kc * OUTC);
      for (int idx = tid; idx < KC * OUTC / 4; idx += 256){
        int kk   = idx / (OUTC / 4);
        int rest = idx % (OUTC / 4);
        int bcg  = rest >> 2;
        int j4   = rest & 3;
        float4 v = Wv[idx];
        *(float4*)&ws[kk][bcg * 16 + ((j4 + bcg) & 3) * 4] = v;
      }
    }
    {
      for (int idx = tid; idx < ROWS * (KC / 4); idx += 256){
        int r = idx / (KC / 4);
        int q = idx % (KC / 4);
        int row = row0 + r;
        float4 v = make_float4(0.f, 0.f, 0.f, 0.f);
        if (row < n) v = *(const float4*)&X[(size_t)row * K + kc + q * 4];
        xs[r][q * 4 + 0] = v.x; xs[r][q * 4 + 1] = v.y;
        xs[r][q * 4 + 2] = v.z; xs[r][q * 4 + 3] = v.w;
      }
    }
    __syncthreads();

    #pragma unroll 4
    for (int k = 0; k < KC; ++k){
      float wv[16];
      #pragma unroll
      for (int j4 = 0; j4 < 4; ++j4){
        float4 v = *(const float4*)&ws[k][cg * 16 + ((j4 + cg) & 3) * 4];
        wv[j4 * 4 + 0] = v.x; wv[j4 * 4 + 1] = v.y;
        wv[j4 * 4 + 2] = v.z; wv[j4 * 4 + 3] = v.w;
      }
      #pragma unroll
      for (int r = 0; r < RPT; ++r){
        float xv = xs[slot * RPT + r][k];
        #pragma unroll
        for (int j = 0; j < 16; ++j) acc[r][j] = fmaf(xv, wv[j], acc[r][j]);
      }
    }
    __syncthreads();
  }

  #pragma unroll
  for (int r = 0; r < RPT; ++r){
    int rb  = slot * RPT + r;
    int row = row0 + rb;
    float ps = 0.f, pd = 0.f;
    #pragma unroll
    for (int j = 0; j < 16; ++j){
      int col = cg * 16 + j;
      ps = fmaf(acc[r][j], att_s[col], ps);
      pd = fmaf(acc[r][j], att_d[col], pd);
    }
    pS[rb][cg] = ps; pD[rb][cg] = pd;
    if (row < n){
      #pragma unroll
      for (int j4 = 0; j4 < 4; ++j4){
        *(float4*)&H[(size_t)row * OUTC + cg * 16 + j4 * 4] =
          make_float4(acc[r][j4*4], acc[r][j4*4+1], acc[r][j4*4+2], acc[r][j4*4+3]);
      }
    }
  }
  __syncthreads();
  for (int rb = tid; rb < ROWS; rb += 256){
    int row = row0 + rb;
    if (row >= n) continue;
    #pragma unroll
    for (int h = 0; h < HEADS; ++h){
      float s = 0.f, d2 = 0.f;
      #pragma unroll
      for (int q = 0; q < CGPH; ++q){ s += pS[rb][h*CGPH + q]; d2 += pD[rb][h*CGPH + q]; }
      ASRC[(size_t)row * HEADS + h] = s;
      ADST[(size_t)row * HEADS + h] = d2;
    }
  }
}

// ---------------- dst-centric softmax aggregation + bias + ELU ----------------
// EG=2 edge-groups per dst: lanes-per-dst = (CH/4)*2. Each group processes a
// contiguous half of the dst's edge list with a 4-edge software pipeline
// (next 4 csr indices prefetched while current 4 rows are gathered).
// Partial (acc, wsum) combined across the two groups via one __shfl_xor.

template<int CH, int HEADS>
__global__ __launch_bounds__(256) void k_aggregate(
    const float* __restrict__ Hmsg, const float* __restrict__ ASRC,
    const float* __restrict__ ADST, const int* __restrict__ off,
    const int* __restrict__ csr, const float* __restrict__ bias,
    float* __restrict__ OUT, int n)
{
  constexpr int CL  = CH / 4;        // channel lanes per group (32 / 16)
  constexpr int LPD = CL * 2;        // lanes per dst (64 / 32)
  constexpr int DPB = 256 / LPD;     // dsts per block (4 / 8)
  constexpr int CPH = CH / HEADS;

  const int tid  = threadIdx.x;
  const int ld   = tid / LPD;
  const int sub  = tid % LPD;
  const int g    = sub / CL;         // edge group 0/1
  const int cl   = sub % CL;
  const int c0   = cl * 4;
  const int h    = c0 / CPH;
  const int d    = blockIdx.x * DPB + ld;
  if (d >= n) return;

  const float adst = ADST[(size_t)d * HEADS + h];

  float wsum = 0.f;
  float4 acc = make_float4(0.f, 0.f, 0.f, 0.f);
  if (g == 0){
    // self loop
    float t = ASRC[(size_t)d * HEADS + h] + adst;
    float w = __expf(fmaxf(t, 0.2f * t));
    float4 hv = *(const float4*)&Hmsg[(size_t)d * CH + c0];
    wsum = w;
    acc = make_float4(w * hv.x, w * hv.y, w * hv.z, w * hv.w);
  }

  const int s0 = off[d], s1 = off[d + 1];
  const int cnt = s1 - s0;
  const int lo = s0 + ((cnt * g) >> 1);
  const int hi = s0 + ((cnt * (g + 1)) >> 1);

  int p = lo;
  // pipeline prologue (csr has +8 slack; over-read values are never used OOB)
  int ia = csr[p], ib = csr[p + 1], ic = csr[p + 2], id_ = csr[p + 3];
  for (; p + 4 <= hi; p += 4){
    int ja = csr[p + 4], jb = csr[p + 5], jc = csr[p + 6], jd = csr[p + 7];
    float ta = ASRC[(size_t)ia * HEADS + h] + adst;
    float tb = ASRC[(size_t)ib * HEADS + h] + adst;
    float tc = ASRC[(size_t)ic * HEADS + h] + adst;
    float td = ASRC[(size_t)id_ * HEADS + h] + adst;
    float4 ha = *(const float4*)&Hmsg[(size_t)ia * CH + c0];
    float4 hb = *(const float4*)&Hmsg[(size_t)ib * CH + c0];
    float4 hc = *(const float4*)&Hmsg[(size_t)ic * CH + c0];
    float4 hd = *(const float4*)&Hmsg[(size_t)id_ * CH + c0];
    float wa = __expf(fmaxf(ta, 0.2f * ta));
    float wb = __expf(fmaxf(tb, 0.2f * tb));
    float wc = __expf(fmaxf(tc, 0.2f * tc));
    float wd = __expf(fmaxf(td, 0.2f * td));
    acc.x = fmaf(wa, ha.x, acc.x); acc.y = fmaf(wa, ha.y, acc.y);
    acc.z = fmaf(wa, ha.z, acc.z); acc.w = fmaf(wa, ha.w, acc.w);
    acc.x = fmaf(wb, hb.x, acc.x); acc.y = fmaf(wb, hb.y, acc.y);
    acc.z = fmaf(wb, hb.z, acc.z); acc.w = fmaf(wb, hb.w, acc.w);
    acc.x = fmaf(wc, hc.x, acc.x); acc.y = fmaf(wc, hc.y, acc.y);
    acc.z = fmaf(wc, hc.z, acc.z); acc.w = fmaf(wc, hc.w, acc.w);
    acc.x = fmaf(wd, hd.x, acc.x); acc.y = fmaf(wd, hd.y, acc.y);
    acc.z = fmaf(wd, hd.z, acc.z); acc.w = fmaf(wd, hd.w, acc.w);
    wsum += (wa + wb) + (wc + wd);
    ia = ja; ib = jb; ic = jc; id_ = jd;
  }
  for (; p < hi; ++p){
    int s = csr[p];
    float t = ASRC[(size_t)s * HEADS + h] + adst;
    float4 hv = *(const float4*)&Hmsg[(size_t)s * CH + c0];
    float w = __expf(fmaxf(t, 0.2f * t));
    acc.x = fmaf(w, hv.x, acc.x); acc.y = fmaf(w, hv.y, acc.y);
    acc.z = fmaf(w, hv.z, acc.z); acc.w = fmaf(w, hv.w, acc.w);
    wsum += w;
  }

  // combine the two edge groups (lanes differ by bit CL within the dst's span)
  acc.x += __shfl_xor(acc.x, CL);
  acc.y += __shfl_xor(acc.y, CL);
  acc.z += __shfl_xor(acc.z, CL);
  acc.w += __shfl_xor(acc.w, CL);
  wsum  += __shfl_xor(wsum,  CL);

  if (g == 0){
    const float inv = 1.f / (wsum + 1e-16f);
    float o0 = acc.x * inv + bias[c0 + 0];
    float o1 = acc.y * inv + bias[c0 + 1];
    float o2 = acc.z * inv + bias[c0 + 2];
    float o3 = acc.w * inv + bias[c0 + 3];
    float4 r;
    r.x = o0 > 0.f ? o0 : expm1f(o0);
    r.y = o1 > 0.f ? o1 : expm1f(o1);
    r.z = o2 > 0.f ? o2 : expm1f(o2);
    r.w = o3 > 0.f ? o3 : expm1f(o3);
    *(float4*)&OUT[(size_t)d * CH + c0] = r;
  }
}

// ---------------- per-graph mean pool + classifier ----------------

__global__ __launch_bounds__(256) void k_pool(
    const float* __restrict__ H, const int* __restrict__ batch,
    const float* __restrict__ Wc, const float* __restrict__ bc,
    float* __restrict__ out, int n)
{
  int g = blockIdx.x;
  int lo = 0, hi = n;
  while (lo < hi){ int mid = (lo + hi) >> 1; if (batch[mid] < g) lo = mid + 1; else hi = mid; }
  int start = lo;
  lo = start; hi = n;
  while (lo < hi){ int mid = (lo + hi) >> 1; if (batch[mid] < g + 1) lo = mid + 1; else hi = mid; }
  int end = lo;

  int tid = threadIdx.x;
  int c = tid & 63;
  int j = tid >> 6;
  float p = 0.f;
  for (int nn = start + j; nn < end; nn += 4) p += H[(size_t)nn * 64 + c];

  __shared__ float red[4][64];
  __shared__ float mean[64];
  red[j][c] = p;
  __syncthreads();
  if (tid < 64){
    float s = red[0][tid] + red[1][tid] + red[2][tid] + red[3][tid];
    int cnt = end - start;
    mean[tid] = s / (float)(cnt > 1 ? cnt : 1);
  }
  __syncthreads();
  if (tid < 2){
    float o = bc[tid];
    #pragma unroll
    for (int cc = 0; cc < 64; ++cc) o = fmaf(mean[cc], Wc[cc * 2 + tid], o);
    out[g * 2 + tid] = o;
  }
}

// ---------------- launch ----------------

extern "C" void kernel_launch(void* const* d_in, const int* in_sizes, int n_in,
                              void* d_out, int out_size, void* d_ws, size_t ws_size,
                              hipStream_t stream)
{
  const float* x    = (const float*)d_in[0];
  const int*   edge = (const int*)  d_in[1];
  const int*   batch= (const int*)  d_in[2];
  const float* W1   = (const float*)d_in[3];
  const float* as1w = (const float*)d_in[4];
  const float* ad1w = (const float*)d_in[5];
  const float* b1   = (const float*)d_in[6];
  const float* W2   = (const float*)d_in[7];
  const float* as2w = (const float*)d_in[8];
  const float* ad2w = (const float*)d_in[9];
  const float* b2   = (const float*)d_in[10];
  const float* Wc   = (const float*)d_in[11];
  const float* bc   = (const float*)d_in[12];

  const int n = in_sizes[2];          // 100000
  const int e = in_sizes[1] / 2;      // 1600000
  const int* esrc = edge;
  const int* edst = edge + e;

  float* h1  = (float*)d_ws;                    // n*128
  float* h1a = h1  + (size_t)n * 128;           // n*128
  float* as1 = h1a + (size_t)n * 128;           // n*4
  float* ad1 = as1 + (size_t)n * 4;             // n*4
  float* as2 = ad1 + (size_t)n * 4;             // n
  float* ad2 = as2 + (size_t)n;                 // n
  int* counts = (int*)(ad2 + (size_t)n);        // n
  int* offs   = counts + n;                     // n+1
  int* cur    = offs + n + 1;                   // n+1
  int* tmp    = cur + n + 1;                    // n
  int* bsum   = tmp + n;                        // 128
  int* bbase  = bsum + 128;                     // 128
  int* csr    = bbase + 128;                    // e + 8 slack

  const int nb = (n + 1023) / 1024;

  k_zero   <<<(n + 255) / 256, 256, 0, stream>>>(counts, n);
  k_hist   <<<(e + 255) / 256, 256, 0, stream>>>(edst, counts, e);
  k_scan1  <<<nb, 1024, 0, stream>>>(counts, tmp, bsum, n);
  k_scan2  <<<1, 64, 0, stream>>>(bsum, bbase, nb);
  k_scan3  <<<(n + 255) / 256, 256, 0, stream>>>(tmp, bbase, offs, cur, n);
  k_scatter<<<(e + 255) / 256, 256, 0, stream>>>(esrc, edst, cur, csr, e);

  k_gemm_att<128, 4, 8, 4><<<(n + 127) / 128, 256, 0, stream>>>(
      x, W1, as1w, ad1w, h1, as1, ad1, n);
  k_aggregate<128, 4><<<(n + 3) / 4, 256, 0, stream>>>(
      h1, as1, ad1, offs, csr, b1, h1a, n);

  float* h2  = h1;
  float* h2a = h1a;
  k_gemm_att<64, 1, 4, 2><<<(n + 127) / 128, 256, 0, stream>>>(
      h1a, W2, as2w, ad2w, h2, as2, ad2, n);
  k_aggregate<64, 1><<<(n + 7) / 8, 256, 0, stream>>>(
      h2, as2, ad2, offs, csr, b2, h2a, n);

  k_pool<<<64, 256, 0, stream>>>(h2a, batch, Wc, bc, (float*)d_out, n);
}

// Round 4
// 612.259 us; speedup vs baseline: 1.1593x; 1.1593x over previous
//
#include <hip/hip_runtime.h>
#include <math.h>

// ---------------------------------------------------------------------------
// GAT 2-layer + mean-pool + classifier, fp32 end-to-end.
//  - CSR(dst) built on-device each call (atomic-free scatter via rank array)
//  - softmax denominators factor out; no segment-max (logits O(1), fp32 safe)
//  - self loops analytic; dst-centric aggregation, float4 channels, no atomics
//  - aggregation: 2 edge-groups/dst + register-resident 4-edge double-buffer
//    (indices + ASRC + H rows all prefetched -> ~8 b128 gathers in flight)
// ---------------------------------------------------------------------------

// ---------------- CSR build ----------------

__global__ void k_zero(int* __restrict__ p, int n){
  int i = blockIdx.x * 256 + threadIdx.x;
  if (i < n) p[i] = 0;
}

// histogram + per-edge rank (old count value) in one pass
__global__ void k_hist(const int* __restrict__ dst, int* __restrict__ counts,
                       int* __restrict__ rank, int e){
  int i = blockIdx.x * 256 + threadIdx.x;
  if (i < e) rank[i] = atomicAdd(&counts[dst[i]], 1);
}

__global__ __launch_bounds__(1024) void k_scan1(const int* __restrict__ counts,
                                                int* __restrict__ tmp,
                                                int* __restrict__ bsum, int n){
  __shared__ int sh[1024];
  int t = threadIdx.x;
  int i = blockIdx.x * 1024 + t;
  sh[t] = (i < n) ? counts[i] : 0;
  __syncthreads();
  for (int o = 1; o < 1024; o <<= 1){
    int x = (t >= o) ? sh[t - o] : 0;
    __syncthreads();
    sh[t] += x;
    __syncthreads();
  }
  if (i < n) tmp[i] = sh[t];
  if (t == 1023) bsum[blockIdx.x] = sh[t];
}

__global__ void k_scan2(const int* __restrict__ bsum, int* __restrict__ bbase, int nb){
  if (threadIdx.x == 0 && blockIdx.x == 0){
    int run = 0;
    for (int b = 0; b < nb; ++b){ bbase[b] = run; run += bsum[b]; }
  }
}

__global__ void k_scan3(const int* __restrict__ tmp, const int* __restrict__ bbase,
                        int* __restrict__ off, int n){
  int i = blockIdx.x * 256 + threadIdx.x;
  if (i < n){
    off[i + 1] = tmp[i] + bbase[i >> 10];
    if (i == 0) off[0] = 0;
  }
}

// deterministic scatter, no atomics
__global__ void k_scatter(const int* __restrict__ src, const int* __restrict__ dst,
                          const int* __restrict__ rank, const int* __restrict__ off,
                          int* __restrict__ csr, int e){
  int i = blockIdx.x * 256 + threadIdx.x;
  if (i < e) csr[off[dst[i]] + rank[i]] = src[i];
}

// ---------------- fused GEMM (X @ W) + attention dot epilogue ----------------

template<int OUTC, int HEADS, int CGN, int RPT>
__global__ __launch_bounds__(256) void k_gemm_att(
    const float* __restrict__ X, const float* __restrict__ W,
    const float* __restrict__ att_s, const float* __restrict__ att_d,
    float* __restrict__ H, float* __restrict__ ASRC, float* __restrict__ ADST, int n)
{
  constexpr int K = 128;
  constexpr int KC = 32;
  constexpr int ROWS = (256 / CGN) * RPT;   // 128
  constexpr int CGPH = CGN / HEADS;

  __shared__ float ws[KC][OUTC];
  __shared__ float xs[ROWS][KC + 1];
  __shared__ float pS[ROWS][CGN];
  __shared__ float pD[ROWS][CGN];

  const int tid  = threadIdx.x;
  const int cg   = tid % CGN;
  const int slot = tid / CGN;
  const int row0 = blockIdx.x * ROWS;

  float acc[RPT][16];
  #pragma unroll
  for (int r = 0; r < RPT; ++r)
    #pragma unroll
    for (int j = 0; j < 16; ++j) acc[r][j] = 0.f;

  for (int kc = 0; kc < K; kc += KC){
    {
      const float4* Wv = (const float4*)(W + kc * OUTC);
      for (int idx = tid; idx < KC * OUTC / 4; idx += 256){
        int kk   = idx / (OUTC / 4);
        int rest = idx % (OUTC / 4);
        int bcg  = rest >> 2;
        int j4   = rest & 3;
        float4 v = Wv[idx];
        *(float4*)&ws[kk][bcg * 16 + ((j4 + bcg) & 3) * 4] = v;
      }
    }
    {
      for (int idx = tid; idx < ROWS * (KC / 4); idx += 256){
        int r = idx / (KC / 4);
        int q = idx % (KC / 4);
        int row = row0 + r;
        float4 v = make_float4(0.f, 0.f, 0.f, 0.f);
        if (row < n) v = *(const float4*)&X[(size_t)row * K + kc + q * 4];
        xs[r][q * 4 + 0] = v.x; xs[r][q * 4 + 1] = v.y;
        xs[r][q * 4 + 2] = v.z; xs[r][q * 4 + 3] = v.w;
      }
    }
    __syncthreads();

    #pragma unroll 4
    for (int k = 0; k < KC; ++k){
      float wv[16];
      #pragma unroll
      for (int j4 = 0; j4 < 4; ++j4){
        float4 v = *(const float4*)&ws[k][cg * 16 + ((j4 + cg) & 3) * 4];
        wv[j4 * 4 + 0] = v.x; wv[j4 * 4 + 1] = v.y;
        wv[j4 * 4 + 2] = v.z; wv[j4 * 4 + 3] = v.w;
      }
      #pragma unroll
      for (int r = 0; r < RPT; ++r){
        float xv = xs[slot * RPT + r][k];
        #pragma unroll
        for (int j = 0; j < 16; ++j) acc[r][j] = fmaf(xv, wv[j], acc[r][j]);
      }
    }
    __syncthreads();
  }

  #pragma unroll
  for (int r = 0; r < RPT; ++r){
    int rb  = slot * RPT + r;
    int row = row0 + rb;
    float ps = 0.f, pd = 0.f;
    #pragma unroll
    for (int j = 0; j < 16; ++j){
      int col = cg * 16 + j;
      ps = fmaf(acc[r][j], att_s[col], ps);
      pd = fmaf(acc[r][j], att_d[col], pd);
    }
    pS[rb][cg] = ps; pD[rb][cg] = pd;
    if (row < n){
      #pragma unroll
      for (int j4 = 0; j4 < 4; ++j4){
        *(float4*)&H[(size_t)row * OUTC + cg * 16 + j4 * 4] =
          make_float4(acc[r][j4*4], acc[r][j4*4+1], acc[r][j4*4+2], acc[r][j4*4+3]);
      }
    }
  }
  __syncthreads();
  for (int rb = tid; rb < ROWS; rb += 256){
    int row = row0 + rb;
    if (row >= n) continue;
    #pragma unroll
    for (int h = 0; h < HEADS; ++h){
      float s = 0.f, d2 = 0.f;
      #pragma unroll
      for (int q = 0; q < CGPH; ++q){ s += pS[rb][h*CGPH + q]; d2 += pD[rb][h*CGPH + q]; }
      ASRC[(size_t)row * HEADS + h] = s;
      ADST[(size_t)row * HEADS + h] = d2;
    }
  }
}

// ---------------- dst-centric softmax aggregation + bias + ELU ----------------
// 2 edge-groups per dst; register-resident double-buffered 4-edge batches:
// the ENTIRE next batch (clamped idx + ASRC + float4 H rows) is fetched into
// named registers before the current batch is consumed, so ~8 independent
// gathers stay in flight per wave. Tail consumes prefetched registers.

template<int CH, int HEADS>
__global__ __launch_bounds__(256) void k_aggregate(
    const float* __restrict__ Hmsg, const float* __restrict__ ASRC,
    const float* __restrict__ ADST, const int* __restrict__ off,
    const int* __restrict__ csr, const float* __restrict__ bias,
    float* __restrict__ OUT, int n)
{
  constexpr int CL  = CH / 4;        // channel lanes per group (32 / 16)
  constexpr int LPD = CL * 2;        // lanes per dst (64 / 32)
  constexpr int DPB = 256 / LPD;     // dsts per block (4 / 8)
  constexpr int CPH = CH / HEADS;

  const int tid  = threadIdx.x;
  const int ld   = tid / LPD;
  const int sub  = tid % LPD;
  const int g    = sub / CL;         // edge group 0/1
  const int cl   = sub % CL;
  const int c0   = cl * 4;
  const int h    = c0 / CPH;
  const int d    = blockIdx.x * DPB + ld;
  if (d >= n) return;

  const float adst = ADST[(size_t)d * HEADS + h];

  float wsum = 0.f;
  float4 acc = make_float4(0.f, 0.f, 0.f, 0.f);
  if (g == 0){
    float t = ASRC[(size_t)d * HEADS + h] + adst;
    float w = __expf(fmaxf(t, 0.2f * t));
    float4 hv = *(const float4*)&Hmsg[(size_t)d * CH + c0];
    wsum = w;
    acc = make_float4(w * hv.x, w * hv.y, w * hv.z, w * hv.w);
  }

  const int s0 = off[d], s1 = off[d + 1];
  const int cnt = s1 - s0;
  const int lo = s0 + ((cnt * g) >> 1);
  const int hi = s0 + ((cnt * (g + 1)) >> 1);

  int    idx[4];
  float  av[4];
  float4 hv[4];
  int p = lo;

  // prologue: batch 0 fully prefetched (indices clamped -> safe gathers)
  #pragma unroll
  for (int j = 0; j < 4; ++j){
    int q = csr[p + j];                    // csr has +8 slack entries
    idx[j] = (p + j < hi) ? q : 0;
  }
  #pragma unroll
  for (int j = 0; j < 4; ++j) av[j] = ASRC[(size_t)idx[j] * HEADS + h];
  #pragma unroll
  for (int j = 0; j < 4; ++j) hv[j] = *(const float4*)&Hmsg[(size_t)idx[j] * CH + c0];

  for (; p + 4 <= hi; p += 4){
    int    nidx[4];
    float  nav[4];
    float4 nhv[4];
    #pragma unroll
    for (int j = 0; j < 4; ++j){
      int q = csr[p + 4 + j];
      nidx[j] = (p + 4 + j < hi) ? q : 0;
    }
    #pragma unroll
    for (int j = 0; j < 4; ++j) nav[j] = ASRC[(size_t)nidx[j] * HEADS + h];
    #pragma unroll
    for (int j = 0; j < 4; ++j) nhv[j] = *(const float4*)&Hmsg[(size_t)nidx[j] * CH + c0];

    #pragma unroll
    for (int j = 0; j < 4; ++j){
      float t = av[j] + adst;
      float w = __expf(fmaxf(t, 0.2f * t));
      acc.x = fmaf(w, hv[j].x, acc.x); acc.y = fmaf(w, hv[j].y, acc.y);
      acc.z = fmaf(w, hv[j].z, acc.z); acc.w = fmaf(w, hv[j].w, acc.w);
      wsum += w;
    }
    #pragma unroll
    for (int j = 0; j < 4; ++j){ idx[j] = nidx[j]; av[j] = nav[j]; hv[j] = nhv[j]; }
  }

  // tail: 0..3 edges, already prefetched
  const int r = hi - p;
  #pragma unroll
  for (int j = 0; j < 4; ++j){
    if (j < r){
      float t = av[j] + adst;
      float w = __expf(fmaxf(t, 0.2f * t));
      acc.x = fmaf(w, hv[j].x, acc.x); acc.y = fmaf(w, hv[j].y, acc.y);
      acc.z = fmaf(w, hv[j].z, acc.z); acc.w = fmaf(w, hv[j].w, acc.w);
      wsum += w;
    }
  }

  // combine the two edge groups
  acc.x += __shfl_xor(acc.x, CL);
  acc.y += __shfl_xor(acc.y, CL);
  acc.z += __shfl_xor(acc.z, CL);
  acc.w += __shfl_xor(acc.w, CL);
  wsum  += __shfl_xor(wsum,  CL);

  if (g == 0){
    const float inv = 1.f / (wsum + 1e-16f);
    float o0 = acc.x * inv + bias[c0 + 0];
    float o1 = acc.y * inv + bias[c0 + 1];
    float o2 = acc.z * inv + bias[c0 + 2];
    float o3 = acc.w * inv + bias[c0 + 3];
    float4 rr;
    rr.x = o0 > 0.f ? o0 : expm1f(o0);
    rr.y = o1 > 0.f ? o1 : expm1f(o1);
    rr.z = o2 > 0.f ? o2 : expm1f(o2);
    rr.w = o3 > 0.f ? o3 : expm1f(o3);
    *(float4*)&OUT[(size_t)d * CH + c0] = rr;
  }
}

// ---------------- per-graph mean pool + classifier ----------------

__global__ __launch_bounds__(256) void k_pool(
    const float* __restrict__ H, const int* __restrict__ batch,
    const float* __restrict__ Wc, const float* __restrict__ bc,
    float* __restrict__ out, int n)
{
  int g = blockIdx.x;
  int lo = 0, hi = n;
  while (lo < hi){ int mid = (lo + hi) >> 1; if (batch[mid] < g) lo = mid + 1; else hi = mid; }
  int start = lo;
  lo = start; hi = n;
  while (lo < hi){ int mid = (lo + hi) >> 1; if (batch[mid] < g + 1) lo = mid + 1; else hi = mid; }
  int end = lo;

  int tid = threadIdx.x;
  int c = tid & 63;
  int j = tid >> 6;
  float p = 0.f;
  for (int nn = start + j; nn < end; nn += 4) p += H[(size_t)nn * 64 + c];

  __shared__ float red[4][64];
  __shared__ float mean[64];
  red[j][c] = p;
  __syncthreads();
  if (tid < 64){
    float s = red[0][tid] + red[1][tid] + red[2][tid] + red[3][tid];
    int cnt = end - start;
    mean[tid] = s / (float)(cnt > 1 ? cnt : 1);
  }
  __syncthreads();
  if (tid < 2){
    float o = bc[tid];
    #pragma unroll
    for (int cc = 0; cc < 64; ++cc) o = fmaf(mean[cc], Wc[cc * 2 + tid], o);
    out[g * 2 + tid] = o;
  }
}

// ---------------- launch ----------------

extern "C" void kernel_launch(void* const* d_in, const int* in_sizes, int n_in,
                              void* d_out, int out_size, void* d_ws, size_t ws_size,
                              hipStream_t stream)
{
  const float* x    = (const float*)d_in[0];
  const int*   edge = (const int*)  d_in[1];
  const int*   batch= (const int*)  d_in[2];
  const float* W1   = (const float*)d_in[3];
  const float* as1w = (const float*)d_in[4];
  const float* ad1w = (const float*)d_in[5];
  const float* b1   = (const float*)d_in[6];
  const float* W2   = (const float*)d_in[7];
  const float* as2w = (const float*)d_in[8];
  const float* ad2w = (const float*)d_in[9];
  const float* b2   = (const float*)d_in[10];
  const float* Wc   = (const float*)d_in[11];
  const float* bc   = (const float*)d_in[12];

  const int n = in_sizes[2];          // 100000
  const int e = in_sizes[1] / 2;      // 1600000
  const int* esrc = edge;
  const int* edst = edge + e;

  float* h1  = (float*)d_ws;                    // n*128
  float* h1a = h1  + (size_t)n * 128;           // n*128
  float* as1 = h1a + (size_t)n * 128;           // n*4
  float* ad1 = as1 + (size_t)n * 4;             // n*4
  float* as2 = ad1 + (size_t)n * 4;             // n
  float* ad2 = as2 + (size_t)n;                 // n
  int* counts = (int*)(ad2 + (size_t)n);        // n
  int* offs   = counts + n;                     // n+1
  int* tmp    = offs + n + 1;                   // n
  int* bsum   = tmp + n;                        // 128
  int* bbase  = bsum + 128;                     // 128
  int* rank   = bbase + 128;                    // e
  int* csr    = rank + e;                       // e + 8 slack

  const int nb = (n + 1023) / 1024;

  k_zero   <<<(n + 255) / 256, 256, 0, stream>>>(counts, n);
  k_hist   <<<(e + 255) / 256, 256, 0, stream>>>(edst, counts, rank, e);
  k_scan1  <<<nb, 1024, 0, stream>>>(counts, tmp, bsum, n);
  k_scan2  <<<1, 64, 0, stream>>>(bsum, bbase, nb);
  k_scan3  <<<(n + 255) / 256, 256, 0, stream>>>(tmp, bbase, offs, n);
  k_scatter<<<(e + 255) / 256, 256, 0, stream>>>(esrc, edst, rank, offs, csr, e);

  k_gemm_att<128, 4, 8, 4><<<(n + 127) / 128, 256, 0, stream>>>(
      x, W1, as1w, ad1w, h1, as1, ad1, n);
  k_aggregate<128, 4><<<(n + 3) / 4, 256, 0, stream>>>(
      h1, as1, ad1, offs, csr, b1, h1a, n);

  float* h2  = h1;
  float* h2a = h1a;
  k_gemm_att<64, 1, 4, 2><<<(n + 127) / 128, 256, 0, stream>>>(
      h1a, W2, as2w, ad2w, h2, as2, ad2, n);
  k_aggregate<64, 1><<<(n + 7) / 8, 256, 0, stream>>>(
      h2, as2, ad2, offs, csr, b2, h2a, n);

  k_pool<<<64, 256, 0, stream>>>(h2a, batch, Wc, bc, (float*)d_out, n);
}